// Round 5
// baseline (32.023 us; speedup 1.0000x reference)
//
#include <hip/hip_runtime.h>

typedef __attribute__((ext_vector_type(8))) short bf16x8;
typedef __attribute__((ext_vector_type(4))) float f32x4;

__device__ __forceinline__ unsigned short f2bf(float f){
  union { float f; unsigned int u; } v; v.f = f;
  unsigned int u = v.u;
  return (unsigned short)((u + 0x7FFFu + ((u >> 16) & 1u)) >> 16);  // RNE
}

__device__ __forceinline__ float fast_tanh(float x){
  x = fminf(15.f, fmaxf(-15.f, x));
  float e = __expf(2.f * x);
  return (e - 1.f) / (e + 1.f);
}

__device__ __forceinline__ float dot128(const float* __restrict__ a,
                                        const float* __restrict__ b){
  float s = 0.f;
  for (int c = 0; c < 128; c += 4){
    float4 x = *(const float4*)(a + c);
    float4 y = *(const float4*)(b + c);
    s += x.x*y.x + x.y*y.y + x.z*y.z + x.w*y.w;
  }
  return s;
}

#define GRPSUM(x) { x += __shfl_xor(x, 1); x += __shfl_xor(x, 2); \
                    x += __shfl_xor(x, 4); x += __shfl_xor(x, 8); }

// ---------------------------------------------------------------------------
// ws float layout:
//   f[0 .. 6144)    : Bpack   — MFMA1 B-frags (12288 bf16), layer-1 weights
//   f[6144 .. 6912) : B2pack  — MFMA2' B-frags (1536 bf16): 3 tiles
//   f[6912 .. 6944) : u'[h] = rs*(Wk2[h].bq2)
//   f[6944 .. 6976) : wv[h] = Wv2[h].Wval[0:128]
//   f[6976] = rs*(bk2.bq2)   f[6977] = bv2.Wval[0:128]
// ---------------------------------------------------------------------------
__global__ __launch_bounds__(64) void k0_kernel(
    const float* __restrict__ Wk1, const float* __restrict__ Wq1, const float* __restrict__ Wv1,
    const float* __restrict__ Wk2, const float* __restrict__ bk2,
    const float* __restrict__ Wq2, const float* __restrict__ bq2,
    const float* __restrict__ Wv2, const float* __restrict__ bv2,
    const float* __restrict__ Wval, float* __restrict__ ws)
{
  const int tid = blockIdx.x * 64 + threadIdx.x;  // 0..4095
  const float rs = 0.08838834764831845f;          // 1/sqrt(128)
  unsigned short* bp = (unsigned short*)ws;
  unsigned short* b2 = (unsigned short*)(ws + 6144);

  if (tid < 1536){
    const int e = tid & 7, l = (tid >> 3) & 63, tt = tid >> 9;
    const int g = (l >> 4) * 8 + e;
    float val = 0.f;
    if (tt < 2){
      const int h = (l & 15) + tt * 16;
      val = rs * dot128(Wk2 + h * 128, Wq2 + g * 128);
    } else if ((l & 15) == 0){
      val = rs * dot128(Wq2 + g * 128, bk2);
    }
    b2[tid] = f2bf(val);
  } else if (tid < 1600){
    const int h = tid - 1536;
    if (h < 32) ws[6912 + h] = rs * dot128(Wk2 + h * 128, bq2);
    else        ws[6944 + (h - 32)] = dot128(Wv2 + (h - 32) * 128, Wval);
  } else if (tid == 1600){
    ws[6976] = rs * dot128(bk2, bq2);
  } else if (tid == 1601){
    ws[6977] = dot128(bv2, Wval);
  }

  for (int idx = tid; idx < 12288; idx += 4096){
    const int e  = idx & 7;
    const int l  = (idx >> 3) & 63;
    const int kc = (idx >> 9) & 3;
    const int nt = (idx >> 11) & 1;
    const int m  = idx >> 12;
    const float* W1 = (m == 0) ? Wk1 : ((m == 1) ? Wq1 : Wv1);
    const int krow = kc * 32 + (l >> 4) * 8 + e;
    const int col  = nt * 16 + (l & 15);
    bp[idx] = f2bf(W1[krow * 32 + col]);
  }
}

// ---------------------------------------------------------------------------
// fused2: one BLOCK = one batch. Wave 0: attention (MFMA score path).
// Waves 1-3: noise streaming (all loads issued up-front) + pv/av (wave 1).
// One barrier, then in-block combine. 2048 blocks -> deep CU queueing.
// ---------------------------------------------------------------------------
__global__ __launch_bounds__(256, 2) void fused2_kernel(
    const float* __restrict__ obs,
    const float* __restrict__ policies, const float* __restrict__ actions,
    const float* __restrict__ noise, const float* __restrict__ weights,
    const float* __restrict__ bk1p, const float* __restrict__ bq1p, const float* __restrict__ bv1p,
    const float* __restrict__ Wval, const float* __restrict__ bval,
    const float* __restrict__ ws,
    float* __restrict__ out_x, float* __restrict__ out_alpha)
{
  __shared__ __align__(16) unsigned short hk_s[512];
  __shared__ __align__(16) unsigned short hq_s[512];
  __shared__ __align__(16) unsigned short tq_s[512];
  __shared__ __align__(16) float rql_s[16];
  __shared__ __align__(16) float vvl_s[16];
  __shared__ __align__(16) float nvw[256];
  __shared__ __align__(16) float pvl_s[16], avl_s[16], ovl_s[16];

  const int t = threadIdx.x;
  const int wid = t >> 6, l = t & 63;
  const int b = blockIdx.x;
  const float wscal = weights[0];
  const float bvs = bval[0];

  if (wid == 0){
    // ================= attention wave (validated r3/r4 path) =================
    const int li = l & 15, gp = l >> 4;

    const float* orow = obs + (size_t)(b * 16 + li) * 128 + gp * 8;
    float4 ob[8];
#pragma unroll
    for (int kc = 0; kc < 4; kc++){
      ob[kc * 2]     = *(const float4*)(orow + kc * 32);
      ob[kc * 2 + 1] = *(const float4*)(orow + kc * 32 + 4);
    }

    const bf16x8* bp  = (const bf16x8*)ws;
    const bf16x8* b2p = (const bf16x8*)(ws + 6144);
    const bf16x8 b20 = b2p[l], b21 = b2p[64 + l], b22 = b2p[128 + l];
    const float u0 = ws[6912 + li], u1 = ws[6928 + li];
    const float wv0 = ws[6944 + li], wv1 = ws[6960 + li];
    const float ccv = ws[6976], cvv = ws[6977];
    const float bk0 = bk1p[li], bk1v = bk1p[16 + li];
    const float bq0 = bq1p[li], bq1v = bq1p[16 + li];
    const float bv0 = bv1p[li], bv1v = bv1p[16 + li];

    bf16x8 afr[4];
#pragma unroll
    for (int kc = 0; kc < 4; kc++){
      bf16x8 a;
      a[0]=(short)f2bf(ob[kc*2].x); a[1]=(short)f2bf(ob[kc*2].y);
      a[2]=(short)f2bf(ob[kc*2].z); a[3]=(short)f2bf(ob[kc*2].w);
      a[4]=(short)f2bf(ob[kc*2+1].x); a[5]=(short)f2bf(ob[kc*2+1].y);
      a[6]=(short)f2bf(ob[kc*2+1].z); a[7]=(short)f2bf(ob[kc*2+1].w);
      afr[kc] = a;
    }
    f32x4 acc[6];
#pragma unroll
    for (int mt = 0; mt < 6; mt++){ f32x4 z = {0.f,0.f,0.f,0.f}; acc[mt] = z; }
#pragma unroll
    for (int mt = 0; mt < 6; mt++){
#pragma unroll
      for (int kc = 0; kc < 4; kc++)
        acc[mt] = __builtin_amdgcn_mfma_f32_16x16x32_bf16(afr[kc], bp[(mt*4+kc)*64 + l], acc[mt], 0, 0, 0);
    }

#pragma unroll
    for (int tile = 0; tile < 2; tile++){
      const float bk_ = tile ? bk1v : bk0;
      const float bq_ = tile ? bq1v : bq0;
      f32x4 ck = acc[tile], cq = acc[2 + tile];
#pragma unroll
      for (int r = 0; r < 4; r++){
        hk_s[(gp*4+r)*32 + tile*16 + li] = f2bf(fast_tanh(ck[r] + bk_));
        hq_s[(gp*4+r)*32 + tile*16 + li] = f2bf(fast_tanh(cq[r] + bq_));
      }
    }

    { // vv[j] = wv . tanh(h_v[j]) + cv
      f32x4 c0 = acc[4], c1 = acc[5];
      float vp0 = wv0*fast_tanh(c0[0]+bv0) + wv1*fast_tanh(c1[0]+bv1v);
      float vp1 = wv0*fast_tanh(c0[1]+bv0) + wv1*fast_tanh(c1[1]+bv1v);
      float vp2 = wv0*fast_tanh(c0[2]+bv0) + wv1*fast_tanh(c1[2]+bv1v);
      float vp3 = wv0*fast_tanh(c0[3]+bv0) + wv1*fast_tanh(c1[3]+bv1v);
      GRPSUM(vp0); GRPSUM(vp1); GRPSUM(vp2); GRPSUM(vp3);
      if (li == 0){
        float4 vq; vq.x = vp0+cvv; vq.y = vp1+cvv; vq.z = vp2+cvv; vq.w = vp3+cvv;
        *(float4*)&vvl_s[gp*4] = vq;
      }
    }

    // MFMA2': tq = hq.(rs*M^T) + rs*u ; tile2 -> rq + cc
    const bf16x8 aq = *(const bf16x8*)(hq_s + li*32 + gp*8);
    f32x4 cu0 = {u0,u0,u0,u0}, cu1 = {u1,u1,u1,u1}, cu2 = {ccv,ccv,ccv,ccv};
    f32x4 tq0 = __builtin_amdgcn_mfma_f32_16x16x32_bf16(aq, b20, cu0, 0, 0, 0);
    f32x4 tq1 = __builtin_amdgcn_mfma_f32_16x16x32_bf16(aq, b21, cu1, 0, 0, 0);
    f32x4 rqt = __builtin_amdgcn_mfma_f32_16x16x32_bf16(aq, b22, cu2, 0, 0, 0);
    if (li == 0){
      float4 rv; rv.x = rqt[0]; rv.y = rqt[1]; rv.z = rqt[2]; rv.w = rqt[3];
      *(float4*)&rql_s[gp*4] = rv;
    }
#pragma unroll
    for (int r = 0; r < 4; r++){
      tq_s[(gp*4+r)*32 + li]      = f2bf(tq0[r]);
      tq_s[(gp*4+r)*32 + 16 + li] = f2bf(tq1[r]);
    }

    // MFMA3: S[j][i] = hk[j] . tq[i]
    const bf16x8 ak = *(const bf16x8*)(hk_s + li*32 + gp*8);
    const bf16x8 bt = *(const bf16x8*)(tq_s + li*32 + gp*8);
    f32x4 zz = {0.f,0.f,0.f,0.f};
    f32x4 S = __builtin_amdgcn_mfma_f32_16x16x32_bf16(ak, bt, zz, 0, 0, 0);
    const float rc = rql_s[li];
    float s0 = S[0]+rc, s1 = S[1]+rc, s2 = S[2]+rc, s3 = S[3]+rc;

    // softmax over senders j
    float mx = fmaxf(fmaxf(s0, s1), fmaxf(s2, s3));
    mx = fmaxf(mx, __shfl_xor(mx, 16)); mx = fmaxf(mx, __shfl_xor(mx, 32));
    float e0 = __expf(s0-mx), e1 = __expf(s1-mx), e2 = __expf(s2-mx), e3 = __expf(s3-mx);
    float sm = e0+e1+e2+e3;
    sm += __shfl_xor(sm, 16); sm += __shfl_xor(sm, 32);
    const float inv = 1.f / sm;
    const float a0 = e0*inv, a1 = e1*inv, a2 = e2*inv, a3 = e3*inv;

    // alpha out via LDS transpose (tq_s reused as float[256])
    float* aT = (float*)tq_s;
    { float4 av4; av4.x = a0; av4.y = a1; av4.z = a2; av4.w = a3;
      *(float4*)&aT[li*16 + gp*4] = av4; }
    { float4 o4 = *(const float4*)&aT[l*4];
      *(float4*)(out_alpha + (size_t)b*256 + l*4) = o4; }

    // ov[i] = sum_j alpha[i][j] * vv[j]
    float4 vq4 = *(const float4*)&vvl_s[gp*4];
    float ovp = a0*vq4.x + a1*vq4.y + a2*vq4.z + a3*vq4.w;
    ovp += __shfl_xor(ovp, 16); ovp += __shfl_xor(ovp, 32);
    if (l < 16) ovl_s[l] = ovp;
  } else {
    // ================= noise waves (1..3): rows 88/88/80 ====================
    const int wn = wid - 1;
    const int q8 = l & 7, r8 = l >> 3;
    const int rbase = wn * 88 + r8;
    const float* nb = noise + (size_t)b * 8192;
    const float4 wv4 = *(const float4*)(Wval + 128 + q8 * 4);

    // pol/act loads (wave 1 only) issued before noise loads
    float4 pA0, pA1, aA0, aA1, wpa, wpb;
    const int jp = l >> 2, seg = l & 3;
    if (wid == 1){
      const float* pp = policies + (size_t)(b * 16 + jp) * 32 + seg * 8;
      const float* ap = actions  + (size_t)(b * 16 + jp) * 32 + seg * 8;
      pA0 = *(const float4*)(pp);
      pA1 = *(const float4*)(pp + 4);
      aA0 = *(const float4*)(ap);
      aA1 = *(const float4*)(ap + 4);
      wpa = *(const float4*)(Wval + 128 + seg * 8);
      wpb = *(const float4*)(Wval + 132 + seg * 8);
    }

    // issue ALL noise loads up-front (one latency exposure per wave)
    float4 nz[11];
#pragma unroll
    for (int p = 0; p < 11; p++){
      const int row = rbase + p * 8;
      if (row < 256) nz[p] = *(const float4*)(nb + row * 32 + q8 * 4);
    }
    // consume
#pragma unroll
    for (int p = 0; p < 11; p++){
      const int row = rbase + p * 8;
      if (row < 256){
        float s = nz[p].x*wv4.x + nz[p].y*wv4.y + nz[p].z*wv4.z + nz[p].w*wv4.w;
        s += __shfl_xor(s, 1); s += __shfl_xor(s, 2); s += __shfl_xor(s, 4);
        if (q8 == 0) nvw[row] = s;
      }
    }

    if (wid == 1){
      float pvv = pA0.x*wpa.x + pA0.y*wpa.y + pA0.z*wpa.z + pA0.w*wpa.w
                + pA1.x*wpb.x + pA1.y*wpb.y + pA1.z*wpb.z + pA1.w*wpb.w;
      float avv = aA0.x*wpa.x + aA0.y*wpa.y + aA0.z*wpa.z + aA0.w*wpa.w
                + aA1.x*wpb.x + aA1.y*wpb.y + aA1.z*wpb.z + aA1.w*wpb.w;
      pvv += __shfl_xor(pvv, 1); pvv += __shfl_xor(pvv, 2);
      avv += __shfl_xor(avv, 1); avv += __shfl_xor(avv, 2);
      if (seg == 0){ pvl_s[jp] = pvv; avl_s[jp] = avv; }
    }
  }

  __syncthreads();

  // ================= combine (all 256 threads): out[i=t>>4][j=t&15] ========
  {
    const int j = t & 15;
    const float pv = pvl_s[j], av = avl_s[j];
    const float zval = wscal * av + (1.f - wscal) * pv + nvw[t];
    float zs = zval;
    GRPSUM(zs);
    out_x[(size_t)b * 256 + t] = ovl_s[t >> 4] + (pv - zval + zs) * 0.0625f + bvs;
  }
}

// ---------------------------------------------------------------------------
extern "C" void kernel_launch(void* const* d_in, const int* in_sizes, int n_in,
                              void* d_out, int out_size, void* d_ws, size_t ws_size,
                              hipStream_t stream)
{
  const float* obs      = (const float*)d_in[0];
  const float* policies = (const float*)d_in[1];
  const float* actions  = (const float*)d_in[2];
  const float* weights  = (const float*)d_in[3];
  const float* noise    = (const float*)d_in[4];
  const float* Wk1  = (const float*)d_in[5];
  const float* bk1  = (const float*)d_in[6];
  const float* Wk2  = (const float*)d_in[7];
  const float* bk2  = (const float*)d_in[8];
  const float* Wq1  = (const float*)d_in[9];
  const float* bq1  = (const float*)d_in[10];
  const float* Wq2  = (const float*)d_in[11];
  const float* bq2  = (const float*)d_in[12];
  const float* Wv1  = (const float*)d_in[13];
  const float* bv1  = (const float*)d_in[14];
  const float* Wv2  = (const float*)d_in[15];
  const float* bv2  = (const float*)d_in[16];
  const float* Wval = (const float*)d_in[17];
  const float* bval = (const float*)d_in[18];

  float* out = (float*)d_out;
  float* ws  = (float*)d_ws;

  const int NODES = in_sizes[0] / 128;
  const int B = NODES / 16;

  float* out_x     = out;
  float* out_alpha = out + (size_t)NODES * 16;

  hipLaunchKernelGGL(k0_kernel, dim3(64), dim3(64), 0, stream,
                     Wk1, Wq1, Wv1, Wk2, bk2, Wq2, bq2, Wv2, bv2, Wval, ws);
  hipLaunchKernelGGL(fused2_kernel, dim3(B), dim3(256), 0, stream,
                     obs, policies, actions, noise, weights,
                     bk1, bq1, bv1, Wval, bval, ws,
                     out_x, out_alpha);
}

// Round 6
// 29.222 us; speedup vs baseline: 1.0959x; 1.0959x over previous
//
#include <hip/hip_runtime.h>

typedef __attribute__((ext_vector_type(8))) short bf16x8;
typedef __attribute__((ext_vector_type(4))) float f32x4;

__device__ __forceinline__ unsigned short f2bf(float f){
  union { float f; unsigned int u; } v; v.f = f;
  unsigned int u = v.u;
  return (unsigned short)((u + 0x7FFFu + ((u >> 16) & 1u)) >> 16);  // RNE
}

__device__ __forceinline__ float fast_tanh(float x){
  x = fminf(15.f, fmaxf(-15.f, x));
  float e = __expf(2.f * x);
  return (e - 1.f) / (e + 1.f);
}

__device__ __forceinline__ float dot128(const float* __restrict__ a,
                                        const float* __restrict__ b){
  float s = 0.f;
  for (int c = 0; c < 128; c += 4){
    float4 x = *(const float4*)(a + c);
    float4 y = *(const float4*)(b + c);
    s += x.x*y.x + x.y*y.y + x.z*y.z + x.w*y.w;
  }
  return s;
}

#define GRPSUM(x) { x += __shfl_xor(x, 1); x += __shfl_xor(x, 2); \
                    x += __shfl_xor(x, 4); x += __shfl_xor(x, 8); }

// ws float layout:
//   f[0 .. 6144)    : Bpack   — MFMA1 B-frags (12288 bf16), layer-1 weights
//   f[6144 .. 6912) : B2pack  — MFMA2' B-frags (1536 bf16): 3 tiles
//   f[6912 .. 6944) : u'[h] = rs*(Wk2[h].bq2)
//   f[6944 .. 6976) : wv[h] = Wv2[h].Wval[0:128]
//   f[6976] = rs*(bk2.bq2)   f[6977] = bv2.Wval[0:128]

// ---------------------------------------------------------------------------
// KN: blocks 0..3 compute tables (k0 work); blocks 4..B+3: noise streaming +
// pv/av + PRD combine (WITHOUT ov term) -> out_x partial. No dependence on
// tables in the noise path, so table latency hides in the noise shadow.
// ---------------------------------------------------------------------------
__global__ __launch_bounds__(256) void kn_kernel(
    const float* __restrict__ policies, const float* __restrict__ actions,
    const float* __restrict__ noise, const float* __restrict__ weights,
    const float* __restrict__ Wval, const float* __restrict__ bval,
    const float* __restrict__ Wk1, const float* __restrict__ Wq1, const float* __restrict__ Wv1,
    const float* __restrict__ Wk2, const float* __restrict__ bk2,
    const float* __restrict__ Wq2, const float* __restrict__ bq2,
    const float* __restrict__ Wv2, const float* __restrict__ bv2,
    float* __restrict__ ws, float* __restrict__ out_x)
{
  const int t = threadIdx.x;

  if ((int)blockIdx.x < 4){
    // ================= table blocks (k0 work, re-indexed) ==================
    const int tid2 = blockIdx.x * 256 + t;   // 0..1023
    const float rs = 0.08838834764831845f;   // 1/sqrt(128)
    unsigned short* bp = (unsigned short*)ws;
    unsigned short* b2 = (unsigned short*)(ws + 6144);

    for (int d = tid2; d < 1602; d += 1024){
      if (d < 1536){
        const int e = d & 7, l = (d >> 3) & 63, tt = d >> 9;
        const int g = (l >> 4) * 8 + e;
        float val = 0.f;
        if (tt < 2){
          const int h = (l & 15) + tt * 16;
          val = rs * dot128(Wk2 + h * 128, Wq2 + g * 128);
        } else if ((l & 15) == 0){
          val = rs * dot128(Wq2 + g * 128, bk2);
        }
        b2[d] = f2bf(val);
      } else if (d < 1600){
        const int h = d - 1536;
        if (h < 32) ws[6912 + h] = rs * dot128(Wk2 + h * 128, bq2);
        else        ws[6944 + (h - 32)] = dot128(Wv2 + (h - 32) * 128, Wval);
      } else if (d == 1600){
        ws[6976] = rs * dot128(bk2, bq2);
      } else { // d == 1601
        ws[6977] = dot128(bv2, Wval);
      }
    }
    for (int idx = tid2; idx < 12288; idx += 1024){
      const int e  = idx & 7;
      const int l  = (idx >> 3) & 63;
      const int kc = (idx >> 9) & 3;
      const int nt = (idx >> 11) & 1;
      const int m  = idx >> 12;
      const float* W1 = (m == 0) ? Wk1 : ((m == 1) ? Wq1 : Wv1);
      const int krow = kc * 32 + (l >> 4) * 8 + e;
      const int col  = nt * 16 + (l & 15);
      bp[idx] = f2bf(W1[krow * 32 + col]);
    }
    return;
  }

  // ================= noise blocks: one block = one batch ===================
  __shared__ __align__(16) float nvw[256];
  __shared__ __align__(16) float pvl[16], avl[16];

  const int b = blockIdx.x - 4;
  const int w = t >> 6, l = t & 63;
  const int q8 = l & 7, r8 = l >> 3;
  const float4 wv4 = *(const float4*)(Wval + 128 + q8 * 4);

  // pv/av loads (wave 0 only), issued before noise loads
  float4 pA0, pA1, aA0, aA1, wpa, wpb;
  const int jp = l >> 2, seg = l & 3;
  if (w == 0){
    const float* pp = policies + (size_t)(b * 16 + jp) * 32 + seg * 8;
    const float* ap = actions  + (size_t)(b * 16 + jp) * 32 + seg * 8;
    pA0 = *(const float4*)(pp);
    pA1 = *(const float4*)(pp + 4);
    aA0 = *(const float4*)(ap);
    aA1 = *(const float4*)(ap + 4);
    wpa = *(const float4*)(Wval + 128 + seg * 8);
    wpb = *(const float4*)(Wval + 132 + seg * 8);
  }

  // 64 rows per wave, 8 up-front float4 loads per lane (1 latency exposure)
  const float* nbl = noise + (size_t)b * 8192 + (w * 64 + r8) * 32 + q8 * 4;
  float4 nz[8];
#pragma unroll
  for (int p = 0; p < 8; p++) nz[p] = *(const float4*)(nbl + p * 256);
#pragma unroll
  for (int p = 0; p < 8; p++){
    float s = nz[p].x*wv4.x + nz[p].y*wv4.y + nz[p].z*wv4.z + nz[p].w*wv4.w;
    s += __shfl_xor(s, 1); s += __shfl_xor(s, 2); s += __shfl_xor(s, 4);
    if (q8 == 0) nvw[w * 64 + p * 8 + r8] = s;
  }

  if (w == 0){
    float pvv = pA0.x*wpa.x + pA0.y*wpa.y + pA0.z*wpa.z + pA0.w*wpa.w
              + pA1.x*wpb.x + pA1.y*wpb.y + pA1.z*wpb.z + pA1.w*wpb.w;
    float avv = aA0.x*wpa.x + aA0.y*wpa.y + aA0.z*wpa.z + aA0.w*wpa.w
              + aA1.x*wpb.x + aA1.y*wpb.y + aA1.z*wpb.z + aA1.w*wpb.w;
    pvv += __shfl_xor(pvv, 1); pvv += __shfl_xor(pvv, 2);
    avv += __shfl_xor(avv, 1); avv += __shfl_xor(avv, 2);
    if (seg == 0){ pvl[jp] = pvv; avl[jp] = avv; }
  }

  __syncthreads();

  if (w == 0){
    // combine (r4-style): lane l -> out[i = l>>2][j = (l&3)*4 + 0..3]
    const float wscal = weights[0];
    const float bvs = bval[0];
    const int i = l >> 2, j0 = (l & 3) * 4;
    float4 pv4 = *(const float4*)&pvl[j0];
    float4 av4 = *(const float4*)&avl[j0];
    float4 nv4 = *(const float4*)&nvw[i * 16 + j0];
    const float om = 1.f - wscal;
    float z0 = wscal * av4.x + om * pv4.x + nv4.x;
    float z1 = wscal * av4.y + om * pv4.y + nv4.y;
    float z2 = wscal * av4.z + om * pv4.z + nv4.z;
    float z3 = wscal * av4.w + om * pv4.w + nv4.w;
    float zs = z0 + z1 + z2 + z3;
    zs += __shfl_xor(zs, 1); zs += __shfl_xor(zs, 2);  // over 16 senders j
    float4 o;
    o.x = (pv4.x - z0 + zs) * 0.0625f + bvs;
    o.y = (pv4.y - z1 + zs) * 0.0625f + bvs;
    o.z = (pv4.z - z2 + zs) * 0.0625f + bvs;
    o.w = (pv4.w - z3 + zs) * 0.0625f + bvs;
    *(float4*)(out_x + (size_t)b * 256 + l * 4) = o;   // NO ov yet
  }
}

// ---------------------------------------------------------------------------
// KA: attention (r3-validated MFMA score path), wave per batch. Writes alpha
// and does out_x += ov[j] (read-modify-write of the KN partial).
// ---------------------------------------------------------------------------
__global__ __launch_bounds__(256) void ka_kernel(
    const float* __restrict__ obs,
    const float* __restrict__ bk1p, const float* __restrict__ bq1p, const float* __restrict__ bv1p,
    const float* __restrict__ ws,
    float* __restrict__ out_x, float* __restrict__ out_alpha)
{
  __shared__ __align__(16) unsigned short hk_s[4][512];
  __shared__ __align__(16) unsigned short hq_s[4][512];
  __shared__ __align__(16) unsigned short tq_s[4][512];
  __shared__ __align__(16) float rql_s[4][16];
  __shared__ __align__(16) float vvl_s[4][16];
  __shared__ __align__(16) float ovl_s[4][16];

  const int t = threadIdx.x;
  const int wid = t >> 6, l = t & 63;
  const int b = blockIdx.x * 4 + wid;
  const int li = l & 15, gp = l >> 4;

  // prefetch obs rows + out_x partial (for the += epilogue)
  const float* orow = obs + (size_t)(b * 16 + li) * 128 + gp * 8;
  float4 ob[8];
#pragma unroll
  for (int kc = 0; kc < 4; kc++){
    ob[kc * 2]     = *(const float4*)(orow + kc * 32);
    ob[kc * 2 + 1] = *(const float4*)(orow + kc * 32 + 4);
  }
  float4 x4 = *(const float4*)(out_x + (size_t)b * 256 + l * 4);

  const bf16x8* bp  = (const bf16x8*)ws;
  const bf16x8* b2p = (const bf16x8*)(ws + 6144);
  const bf16x8 b20 = b2p[l], b21 = b2p[64 + l], b22 = b2p[128 + l];
  const float u0 = ws[6912 + li], u1 = ws[6928 + li];
  const float wv0 = ws[6944 + li], wv1 = ws[6960 + li];
  const float ccv = ws[6976], cvv = ws[6977];
  const float bk0 = bk1p[li], bk1v = bk1p[16 + li];
  const float bq0 = bq1p[li], bq1v = bq1p[16 + li];
  const float bv0 = bv1p[li], bv1v = bv1p[16 + li];

  bf16x8 afr[4];
#pragma unroll
  for (int kc = 0; kc < 4; kc++){
    bf16x8 a;
    a[0]=(short)f2bf(ob[kc*2].x); a[1]=(short)f2bf(ob[kc*2].y);
    a[2]=(short)f2bf(ob[kc*2].z); a[3]=(short)f2bf(ob[kc*2].w);
    a[4]=(short)f2bf(ob[kc*2+1].x); a[5]=(short)f2bf(ob[kc*2+1].y);
    a[6]=(short)f2bf(ob[kc*2+1].z); a[7]=(short)f2bf(ob[kc*2+1].w);
    afr[kc] = a;
  }
  f32x4 acc[6];
#pragma unroll
  for (int mt = 0; mt < 6; mt++){ f32x4 z = {0.f,0.f,0.f,0.f}; acc[mt] = z; }
#pragma unroll
  for (int mt = 0; mt < 6; mt++){
#pragma unroll
    for (int kc = 0; kc < 4; kc++)
      acc[mt] = __builtin_amdgcn_mfma_f32_16x16x32_bf16(afr[kc], bp[(mt*4+kc)*64 + l], acc[mt], 0, 0, 0);
  }

  unsigned short* hkb = hk_s[wid];
  unsigned short* hqb = hq_s[wid];
#pragma unroll
  for (int tile = 0; tile < 2; tile++){
    const float bk_ = tile ? bk1v : bk0;
    const float bq_ = tile ? bq1v : bq0;
    f32x4 ck = acc[tile], cq = acc[2 + tile];
#pragma unroll
    for (int r = 0; r < 4; r++){
      hkb[(gp*4+r)*32 + tile*16 + li] = f2bf(fast_tanh(ck[r] + bk_));
      hqb[(gp*4+r)*32 + tile*16 + li] = f2bf(fast_tanh(cq[r] + bq_));
    }
  }

  { // vv[j] = wv . tanh(h_v[j]) + cv
    f32x4 c0 = acc[4], c1 = acc[5];
    float vp0 = wv0*fast_tanh(c0[0]+bv0) + wv1*fast_tanh(c1[0]+bv1v);
    float vp1 = wv0*fast_tanh(c0[1]+bv0) + wv1*fast_tanh(c1[1]+bv1v);
    float vp2 = wv0*fast_tanh(c0[2]+bv0) + wv1*fast_tanh(c1[2]+bv1v);
    float vp3 = wv0*fast_tanh(c0[3]+bv0) + wv1*fast_tanh(c1[3]+bv1v);
    GRPSUM(vp0); GRPSUM(vp1); GRPSUM(vp2); GRPSUM(vp3);
    if (li == 0){
      float4 vq; vq.x = vp0+cvv; vq.y = vp1+cvv; vq.z = vp2+cvv; vq.w = vp3+cvv;
      *(float4*)&vvl_s[wid][gp*4] = vq;
    }
  }

  // MFMA2': tq = hq.(rs*M^T) + rs*u ; tile2 -> rs*(rq + cc)
  const bf16x8 aq = *(const bf16x8*)(hqb + li*32 + gp*8);
  f32x4 cu0 = {u0,u0,u0,u0}, cu1 = {u1,u1,u1,u1}, cu2 = {ccv,ccv,ccv,ccv};
  f32x4 tq0 = __builtin_amdgcn_mfma_f32_16x16x32_bf16(aq, b20, cu0, 0, 0, 0);
  f32x4 tq1 = __builtin_amdgcn_mfma_f32_16x16x32_bf16(aq, b21, cu1, 0, 0, 0);
  f32x4 rqt = __builtin_amdgcn_mfma_f32_16x16x32_bf16(aq, b22, cu2, 0, 0, 0);
  if (li == 0){
    float4 rv; rv.x = rqt[0]; rv.y = rqt[1]; rv.z = rqt[2]; rv.w = rqt[3];
    *(float4*)&rql_s[wid][gp*4] = rv;
  }
  unsigned short* tqb = tq_s[wid];
#pragma unroll
  for (int r = 0; r < 4; r++){
    tqb[(gp*4+r)*32 + li]      = f2bf(tq0[r]);
    tqb[(gp*4+r)*32 + 16 + li] = f2bf(tq1[r]);
  }

  // MFMA3: S[j][i] = hk[j] . tq[i]
  const bf16x8 ak = *(const bf16x8*)(hkb + li*32 + gp*8);
  const bf16x8 bt = *(const bf16x8*)(tqb + li*32 + gp*8);
  f32x4 zz = {0.f,0.f,0.f,0.f};
  f32x4 S = __builtin_amdgcn_mfma_f32_16x16x32_bf16(ak, bt, zz, 0, 0, 0);
  const float rc = rql_s[wid][li];
  float s0 = S[0]+rc, s1 = S[1]+rc, s2 = S[2]+rc, s3 = S[3]+rc;

  // softmax over senders j (4 regs x 4 lane-groups)
  float mx = fmaxf(fmaxf(s0, s1), fmaxf(s2, s3));
  mx = fmaxf(mx, __shfl_xor(mx, 16)); mx = fmaxf(mx, __shfl_xor(mx, 32));
  float e0 = __expf(s0-mx), e1 = __expf(s1-mx), e2 = __expf(s2-mx), e3 = __expf(s3-mx);
  float sm = e0+e1+e2+e3;
  sm += __shfl_xor(sm, 16); sm += __shfl_xor(sm, 32);
  const float inv = 1.f / sm;
  const float a0 = e0*inv, a1 = e1*inv, a2 = e2*inv, a3 = e3*inv;

  // alpha out via LDS transpose (tq_s reused as float[256])
  float* aT = (float*)tqb;
  { float4 av4; av4.x = a0; av4.y = a1; av4.z = a2; av4.w = a3;
    *(float4*)&aT[li*16 + gp*4] = av4; }
  { float4 o4 = *(const float4*)&aT[l*4];
    *(float4*)(out_alpha + (size_t)b*256 + l*4) = o4; }

  // ov[i] = sum_j alpha[i][j] * vv[j]
  float4 vq4 = *(const float4*)&vvl_s[wid][gp*4];
  float ovp = a0*vq4.x + a1*vq4.y + a2*vq4.z + a3*vq4.w;
  ovp += __shfl_xor(ovp, 16); ovp += __shfl_xor(ovp, 32);
  if (l < 16) ovl_s[wid][l] = ovp;

  // epilogue: out_x += ov[j]  (lane l covers t = l*4..l*4+3, j = (l&3)*4+c)
  {
    float4 ov4 = *(const float4*)&ovl_s[wid][(l & 3) * 4];
    x4.x += ov4.x; x4.y += ov4.y; x4.z += ov4.z; x4.w += ov4.w;
    *(float4*)(out_x + (size_t)b * 256 + l * 4) = x4;
  }
}

// ---------------------------------------------------------------------------
extern "C" void kernel_launch(void* const* d_in, const int* in_sizes, int n_in,
                              void* d_out, int out_size, void* d_ws, size_t ws_size,
                              hipStream_t stream)
{
  const float* obs      = (const float*)d_in[0];
  const float* policies = (const float*)d_in[1];
  const float* actions  = (const float*)d_in[2];
  const float* weights  = (const float*)d_in[3];
  const float* noise    = (const float*)d_in[4];
  const float* Wk1  = (const float*)d_in[5];
  const float* bk1  = (const float*)d_in[6];
  const float* Wk2  = (const float*)d_in[7];
  const float* bk2  = (const float*)d_in[8];
  const float* Wq1  = (const float*)d_in[9];
  const float* bq1  = (const float*)d_in[10];
  const float* Wq2  = (const float*)d_in[11];
  const float* bq2  = (const float*)d_in[12];
  const float* Wv1  = (const float*)d_in[13];
  const float* bv1  = (const float*)d_in[14];
  const float* Wv2  = (const float*)d_in[15];
  const float* bv2  = (const float*)d_in[16];
  const float* Wval = (const float*)d_in[17];
  const float* bval = (const float*)d_in[18];

  float* out = (float*)d_out;
  float* ws  = (float*)d_ws;

  const int NODES = in_sizes[0] / 128;
  const int B = NODES / 16;

  float* out_x     = out;
  float* out_alpha = out + (size_t)NODES * 16;

  hipLaunchKernelGGL(kn_kernel, dim3(B + 4), dim3(256), 0, stream,
                     policies, actions, noise, weights, Wval, bval,
                     Wk1, Wq1, Wv1, Wk2, bk2, Wq2, bq2, Wv2, bv2,
                     ws, out_x);
  hipLaunchKernelGGL(ka_kernel, dim3(B / 4), dim3(256), 0, stream,
                     obs, bk1, bq1, bv1, ws, out_x, out_alpha);
}